// Round 20
// baseline (201.567 us; speedup 1.0000x reference)
//
#include <hip/hip_runtime.h>
#include <math.h>

#define N_NODES 50000
#define N_EDGES 800000
#define D 128
#define NH 8
#define EPS 1e-5f
#define QSCALE 0.08838834764831845f  // 128^-0.5

#define TQ 24   // 16-col tiles in W_qkv (384 cols)
#define TO 8    // 16-col tiles in W_out (128 cols)

typedef __attribute__((ext_vector_type(8))) short short8;
typedef __attribute__((ext_vector_type(4))) float f32x4;

// bf16 round-to-nearest-even helpers (bit-pattern in ushort)
__device__ __forceinline__ unsigned short f2bf_rne(float f) {
    unsigned int u = __float_as_uint(f);
    u += 0x7fff + ((u >> 16) & 1);
    return (unsigned short)(u >> 16);
}
__device__ __forceinline__ float bf2f(unsigned short h) {
    return __uint_as_float(((unsigned int)h) << 16);
}
__device__ __forceinline__ float2 bfpair(unsigned int u) {
    return make_float2(__uint_as_float(u << 16),
                       __uint_as_float(u & 0xffff0000u));
}

// async global->LDS, 16B per lane.
__device__ __forceinline__ void gload_lds16(const void* g, void* l) {
    __builtin_amdgcn_global_load_lds(
        (const __attribute__((address_space(1))) unsigned int*)g,
        (__attribute__((address_space(3))) unsigned int*)l, 16, 0, 0);
}

// gather helpers
__device__ __forceinline__ float qdot(uint4 u, float4 kv) {
    float2 q0 = bfpair(u.x), q1 = bfpair(u.z);
    return q0.x * kv.x + q0.y * kv.y + q1.x * kv.z + q1.y * kv.w;
}
__device__ __forceinline__ void vacc(uint4 u, float w, float& sden,
                                     float& a0, float& a1, float& a2, float& a3) {
    float2 v0 = bfpair(u.y), v1 = bfpair(u.w);
    sden += w;
    a0 += w * v0.x; a1 += w * v0.y; a2 += w * v1.x; a3 += w * v1.y;
}

// ---------------------------------------------------------------------------
// K_prep (+zero fused): split W into bf16 hi/lo, tiled + pre-swizzled; also
// zeroes the histogram buffer.
// ---------------------------------------------------------------------------
__global__ void k_prep(const float* __restrict__ Wqkv, const float* __restrict__ Wout,
                       unsigned short* __restrict__ wq_t, unsigned short* __restrict__ wo_t,
                       int* __restrict__ cnt) {
    const int i = blockIdx.x * blockDim.x + threadIdx.x;
    if (i < N_NODES) cnt[i] = 0;
    if (i < TQ * 256) {
        const int nt = i >> 8, r = (i >> 4) & 15, c8 = i & 15;
        const float* s = Wqkv + (size_t)(nt * 16 + r) * D + c8 * 8;
        short8 h8, l8;
        #pragma unroll
        for (int j = 0; j < 8; j++) {
            float w = s[j];
            unsigned short h = f2bf_rne(w);
            h8[j] = (short)h;
            l8[j] = (short)f2bf_rne(w - bf2f(h));
        }
        const int off = (r * 256 + c8 * 16) ^ ((r & 7) << 4);
        char* base = (char*)wq_t + (size_t)nt * 8192;
        *(short8*)(base + off)        = h8;
        *(short8*)(base + 4096 + off) = l8;
    }
    if (i < TO * 256) {
        const int nt = i >> 8, r = (i >> 4) & 15, c8 = i & 15;
        const float* s = Wout + (size_t)(nt * 16 + r) * D + c8 * 8;
        short8 h8, l8;
        #pragma unroll
        for (int j = 0; j < 8; j++) {
            float w = s[j];
            unsigned short h = f2bf_rne(w);
            h8[j] = (short)h;
            l8[j] = (short)f2bf_rne(w - bf2f(h));
        }
        const int off = (r * 256 + c8 * 16) ^ ((r & 7) << 4);
        char* base = (char*)wo_t + (size_t)nt * 8192;
        *(short8*)(base + off)        = h8;
        *(short8*)(base + 4096 + off) = l8;
    }
}

// ---------------------------------------------------------------------------
// K_hist: histogram + per-edge rank + dist+path summed to bf16 dpsum
// (edge order, coalesced; hides under atomic-return latency).
// ---------------------------------------------------------------------------
__global__ void k_hist(const int* __restrict__ dst,
                       const float* __restrict__ dist, const float* __restrict__ path,
                       int* __restrict__ cnt, int* __restrict__ rank,
                       unsigned short* __restrict__ dps) {
    const int e0 = (blockIdx.x * blockDim.x + threadIdx.x) * 4;
    if (e0 >= N_EDGES) return;                  // N_EDGES % 4 == 0
    const int4 d4 = *(const int4*)(dst + e0);
    int r0 = atomicAdd(&cnt[d4.x], 1);
    int r1 = atomicAdd(&cnt[d4.y], 1);
    int r2 = atomicAdd(&cnt[d4.z], 1);
    int r3 = atomicAdd(&cnt[d4.w], 1);
    #pragma unroll
    for (int j = 0; j < 4; j++) {
        const int e = e0 + j;
        float4 da = *(const float4*)(dist + (size_t)e * 8);
        float4 db = *(const float4*)(dist + (size_t)e * 8 + 4);
        float4 pa = *(const float4*)(path + (size_t)e * 8);
        float4 pb = *(const float4*)(path + (size_t)e * 8 + 4);
        short8 w;
        w[0] = (short)f2bf_rne(da.x + pa.x);
        w[1] = (short)f2bf_rne(da.y + pa.y);
        w[2] = (short)f2bf_rne(da.z + pa.z);
        w[3] = (short)f2bf_rne(da.w + pa.w);
        w[4] = (short)f2bf_rne(db.x + pb.x);
        w[5] = (short)f2bf_rne(db.y + pb.y);
        w[6] = (short)f2bf_rne(db.z + pb.z);
        w[7] = (short)f2bf_rne(db.w + pb.w);
        *(short8*)(dps + (size_t)e * 8) = w;
    }
    *(int4*)(rank + e0) = make_int4(r0, r1, r2, r3);
}

// ---------------------------------------------------------------------------
// CSR scan (hierarchical, 2 kernels)
// ---------------------------------------------------------------------------
#define SCB 1024
#define SCG ((N_NODES + SCB - 1) / SCB)

__global__ void k_scan1(const int* __restrict__ cnt, int* __restrict__ row_start,
                        int* __restrict__ bsum) {
    __shared__ int wsum[16];
    const int tid = threadIdx.x, lane = tid & 63, wid = tid >> 6;
    const int gid = blockIdx.x * SCB + tid;
    const int v = (gid < N_NODES) ? cnt[gid] : 0;

    int x = v;
    #pragma unroll
    for (int off = 1; off < 64; off <<= 1) {
        int t = __shfl_up(x, off);
        if (lane >= off) x += t;
    }
    if (lane == 63) wsum[wid] = x;
    __syncthreads();
    if (wid == 0) {
        int w = (lane < 16) ? wsum[lane] : 0;
        #pragma unroll
        for (int off = 1; off < 16; off <<= 1) {
            int t = __shfl_up(w, off);
            if (lane >= off) w += t;
        }
        if (lane < 16) wsum[lane] = w;
    }
    __syncthreads();
    const int base = (wid > 0) ? wsum[wid - 1] : 0;
    const int incl = base + x;
    if (gid < N_NODES) row_start[gid] = incl - v;
    if (tid == SCB - 1) bsum[blockIdx.x] = incl;
}

__global__ void k_scan2(const int* __restrict__ bsum, int* __restrict__ row_start) {
    __shared__ int boff_s;
    const int tid = threadIdx.x;
    if (tid < 64) {
        int v = (tid < blockIdx.x) ? bsum[tid] : 0;
        #pragma unroll
        for (int off = 1; off < 64; off <<= 1) v += __shfl_xor(v, off);
        if (tid == 0) boff_s = v;
    }
    __syncthreads();
    const int gid = blockIdx.x * SCB + tid;
    if (gid < N_NODES) row_start[gid] += boff_s;
    if (gid == 0) row_start[N_NODES] = N_EDGES;
}

// ---------------------------------------------------------------------------
// K_fill: no atomics, no float math — pos = row_start[dst] + rank;
// copy ssrc (4B) + dpsum short8 (16B) to CSR position. 4 edges/thread.
// ---------------------------------------------------------------------------
__global__ void k_fill(const int* __restrict__ src, const int* __restrict__ dst,
                       const int* __restrict__ rank, const int* __restrict__ row_start,
                       const unsigned short* __restrict__ dps,
                       int* __restrict__ ssrc, unsigned short* __restrict__ dp16) {
    const int e0 = (blockIdx.x * blockDim.x + threadIdx.x) * 4;
    if (e0 >= N_EDGES) return;                  // N_EDGES % 4 == 0
    const int4 s4 = *(const int4*)(src + e0);
    const int4 d4 = *(const int4*)(dst + e0);
    const int4 r4 = *(const int4*)(rank + e0);
    int p0 = row_start[d4.x] + r4.x;
    int p1 = row_start[d4.y] + r4.y;
    int p2 = row_start[d4.z] + r4.z;
    int p3 = row_start[d4.w] + r4.w;
    short8 w0 = *(const short8*)(dps + (size_t)e0 * 8);
    short8 w1 = *(const short8*)(dps + (size_t)(e0 + 1) * 8);
    short8 w2 = *(const short8*)(dps + (size_t)(e0 + 2) * 8);
    short8 w3 = *(const short8*)(dps + (size_t)(e0 + 3) * 8);

    ssrc[p0] = s4.x;  *(short8*)(dp16 + (size_t)p0 * 8) = w0;
    ssrc[p1] = s4.y;  *(short8*)(dp16 + (size_t)p1 * 8) = w1;
    ssrc[p2] = s4.z;  *(short8*)(dp16 + (size_t)p2 * 8) = w2;
    ssrc[p3] = s4.w;  *(short8*)(dp16 + (size_t)p3 * 8) = w3;
}

// ---------------------------------------------------------------------------
// K1: LayerNorm + QKV projection via MFMA bf16x3, LDS-staged W (unchanged).
// ---------------------------------------------------------------------------
__launch_bounds__(256)
__global__ void k_ln_qkv(const float* __restrict__ nf, const float* __restrict__ gamma,
                         const float* __restrict__ beta,
                         const unsigned short* __restrict__ wq_t,
                         const float* __restrict__ bqkv,
                         unsigned short* __restrict__ qv,
                         unsigned short* __restrict__ kb16) {
    __shared__ __align__(16) char lds[2][8192];
    const int lane  = threadIdx.x & 63;
    const int wv    = threadIdx.x >> 6;
    const int nbase = blockIdx.x * 64 + wv * 16;
    const int mrow  = lane & 15;
    const int kg    = lane >> 4;

    int gn = nbase + mrow;
    if (gn >= N_NODES) gn = N_NODES - 1;
    const float* xrow = nf + (size_t)gn * D + kg * 8;
    float4 xa[4], xb[4];
    #pragma unroll
    for (int t = 0; t < 4; t++) {
        xa[t] = *(const float4*)(xrow + t * 32);
        xb[t] = *(const float4*)(xrow + t * 32 + 4);
    }
    float s = 0.f, ss = 0.f;
    #pragma unroll
    for (int t = 0; t < 4; t++) {
        s  += xa[t].x + xa[t].y + xa[t].z + xa[t].w
            + xb[t].x + xb[t].y + xb[t].z + xb[t].w;
        ss += xa[t].x * xa[t].x + xa[t].y * xa[t].y + xa[t].z * xa[t].z + xa[t].w * xa[t].w
            + xb[t].x * xb[t].x + xb[t].y * xb[t].y + xb[t].z * xb[t].z + xb[t].w * xb[t].w;
    }
    s += __shfl_xor(s, 16); ss += __shfl_xor(ss, 16);
    s += __shfl_xor(s, 32); ss += __shfl_xor(ss, 32);
    float mu   = s * (1.f / 128.f);
    float var  = ss * (1.f / 128.f) - mu * mu;
    float rstd = rsqrtf(var + EPS);

    short8 ahi[4], alo[4];
    #pragma unroll
    for (int t = 0; t < 4; t++) {
        const float* gp = gamma + kg * 8 + t * 32;
        const float* bp = beta  + kg * 8 + t * 32;
        float4 g0 = *(const float4*)gp, g1 = *(const float4*)(gp + 4);
        float4 b0 = *(const float4*)bp, b1 = *(const float4*)(bp + 4);
        float xn[8];
        xn[0] = (xa[t].x - mu) * rstd * g0.x + b0.x;
        xn[1] = (xa[t].y - mu) * rstd * g0.y + b0.y;
        xn[2] = (xa[t].z - mu) * rstd * g0.z + b0.z;
        xn[3] = (xa[t].w - mu) * rstd * g0.w + b0.w;
        xn[4] = (xb[t].x - mu) * rstd * g1.x + b1.x;
        xn[5] = (xb[t].y - mu) * rstd * g1.y + b1.y;
        xn[6] = (xb[t].z - mu) * rstd * g1.z + b1.z;
        xn[7] = (xb[t].w - mu) * rstd * g1.w + b1.w;
        #pragma unroll
        for (int j = 0; j < 8; j++) {
            unsigned short h = f2bf_rne(xn[j]);
            ahi[t][j] = (short)h;
            alo[t][j] = (short)f2bf_rne(xn[j] - bf2f(h));
        }
    }

    int boff[4];
    #pragma unroll
    for (int t = 0; t < 4; t++)
        boff[t] = (mrow * 256 + (kg + 4 * t) * 16) ^ ((mrow & 7) << 4);

    {
        const char* g0 = (const char*)wq_t + (size_t)0 * 8192 + wv * 2048 + lane * 16;
        gload_lds16(g0,        lds[0] + wv * 2048);
        gload_lds16(g0 + 1024, lds[0] + wv * 2048 + 1024);
    }
    __syncthreads();

    int cur = 0;
    for (int nt = 0; nt < TQ; ++nt) {
        if (nt + 1 < TQ) {
            const char* g0 = (const char*)wq_t + (size_t)(nt + 1) * 8192 + wv * 2048 + lane * 16;
            gload_lds16(g0,        lds[cur ^ 1] + wv * 2048);
            gload_lds16(g0 + 1024, lds[cur ^ 1] + wv * 2048 + 1024);
        }

        f32x4 acc0 = {0.f, 0.f, 0.f, 0.f};
        f32x4 acc1 = {0.f, 0.f, 0.f, 0.f};
        #pragma unroll
        for (int t = 0; t < 4; t++) {
            short8 bh = *(const short8*)(lds[cur] + boff[t]);
            short8 bl = *(const short8*)(lds[cur] + 4096 + boff[t]);
            acc0 = __builtin_amdgcn_mfma_f32_16x16x32_bf16(ahi[t], bh, acc0, 0, 0, 0);
            acc1 = __builtin_amdgcn_mfma_f32_16x16x32_bf16(alo[t], bh, acc1, 0, 0, 0);
            acc0 = __builtin_amdgcn_mfma_f32_16x16x32_bf16(ahi[t], bl, acc0, 0, 0, 0);
        }

        const int col = nt * 16 + mrow;
        float bias = bqkv[col];
        if (nt < 8) {                 // q -> bf16 qv, pre-scaled, dword-packed
            #pragma unroll
            for (int r = 0; r < 4; r++) {
                int node = nbase + kg * 4 + r;
                unsigned int hq = f2bf_rne((acc0[r] + acc1[r] + bias) * QSCALE);
                unsigned int ph = __shfl_xor((int)hq, 1);
                if (!(mrow & 1) && node < N_NODES) {
                    unsigned int u2 = (hq & 0xffffu) | (ph << 16);
                    *(unsigned int*)(qv + (size_t)node * 256 + ((col >> 1) << 2)) = u2;
                }
            }
        } else if (nt < 16) {         // k -> bf16 kb16, dword-packed
            #pragma unroll
            for (int r = 0; r < 4; r++) {
                int node = nbase + kg * 4 + r;
                unsigned int hq = f2bf_rne(acc0[r] + acc1[r] + bias);
                unsigned int ph = __shfl_xor((int)hq, 1);
                if (!(mrow & 1) && node < N_NODES) {
                    unsigned int u2 = (hq & 0xffffu) | (ph << 16);
                    int ck = col - 128;
                    *(unsigned int*)(kb16 + (size_t)node * 128 + (ck & ~1)) = u2;
                }
            }
        } else {                      // v -> bf16 qv, dword-packed
            #pragma unroll
            for (int r = 0; r < 4; r++) {
                int node = nbase + kg * 4 + r;
                unsigned int hq = f2bf_rne(acc0[r] + acc1[r] + bias);
                unsigned int ph = __shfl_xor((int)hq, 1);
                if (!(mrow & 1) && node < N_NODES) {
                    unsigned int u2 = (hq & 0xffffu) | (ph << 16);
                    int cv = col - 256;
                    *(unsigned int*)(qv + (size_t)node * 256 + ((cv >> 1) << 2) + 2) = u2;
                }
            }
        }

        __syncthreads();
        cur ^= 1;
    }
}

// ---------------------------------------------------------------------------
// K_gather_out (R20): gather + output GEMM fused. Block = 64 nodes, 4 waves.
// Phase 1: wave wv gathers its 16 nodes sequentially (same 4-deep pipeline),
// writing agg rows to LDS ag[64][132] (pitch-132: float4 writes and b128
// reads both at the 32-bank throughput floor). Phase 2: k_out's MFMA GEMM,
// A-fragments from LDS, B-fragments direct from L2-hot pre-swizzled wo_t.
// Eliminates the 51.2MB agg HBM round-trip and one launch. No cross-block
// communication (no XCD-coherence hazard).
// ---------------------------------------------------------------------------
__launch_bounds__(256, 4)
__global__ void k_gather_out(const unsigned short* __restrict__ qv,
                             const unsigned short* __restrict__ kb16,
                             const unsigned short* __restrict__ dp16,
                             const int* __restrict__ row_start,
                             const int* __restrict__ ssrc,
                             const unsigned short* __restrict__ wo_t,
                             const float* __restrict__ bout,
                             const float* __restrict__ nf,
                             float* __restrict__ out) {
    __shared__ float ag[64][132];
    const int lane = threadIdx.x & 63;
    const int wv   = threadIdx.x >> 6;
    const int nbase = blockIdx.x * 64;

    // ---- phase 1: gather 16 nodes per wave ----
    const int half = lane >> 5;            // 0/1: alternate edges
    const int l    = lane & 31;            // dims 4l..4l+3
    const int h    = l >> 2;               // head (4 lanes/head)

    for (int ni = 0; ni < 16; ni++) {
        const int node = nbase + wv * 16 + ni;
        const int nc = (node < N_NODES) ? node : N_NODES - 1;
        int beg = 0, end = 0;
        if (node < N_NODES) { beg = row_start[node]; end = row_start[node + 1]; }

        uint2 ku = *(const uint2*)(kb16 + (size_t)nc * 128 + 4 * l);
        float2 k0 = bfpair(ku.x), k1 = bfpair(ku.y);
        const float4 kv = make_float4(k0.x, k0.y, k1.x, k1.y);
        float sden = 0.f, a0 = 0.f, a1 = 0.f, a2 = 0.f, a3 = 0.f;

        int i = beg + half;
        for (; i + 6 < end; i += 8) {      // 4-deep
            int s0 = ssrc[i], s1 = ssrc[i + 2], s2 = ssrc[i + 4], s3 = ssrc[i + 6];
            uint4 u0 = *(const uint4*)(qv + (size_t)s0 * 256 + l * 8);
            uint4 u1 = *(const uint4*)(qv + (size_t)s1 * 256 + l * 8);
            uint4 u2 = *(const uint4*)(qv + (size_t)s2 * 256 + l * 8);
            uint4 u3 = *(const uint4*)(qv + (size_t)s3 * 256 + l * 8);
            float d0 = bf2f(dp16[(size_t)i * 8 + h]);
            float d1 = bf2f(dp16[(size_t)(i + 2) * 8 + h]);
            float d2 = bf2f(dp16[(size_t)(i + 4) * 8 + h]);
            float d3 = bf2f(dp16[(size_t)(i + 6) * 8 + h]);

            float p0 = qdot(u0, kv), p1 = qdot(u1, kv);
            float p2 = qdot(u2, kv), p3 = qdot(u3, kv);
            p0 += __shfl_xor(p0, 1); p1 += __shfl_xor(p1, 1);
            p2 += __shfl_xor(p2, 1); p3 += __shfl_xor(p3, 1);
            p0 += __shfl_xor(p0, 2); p1 += __shfl_xor(p1, 2);
            p2 += __shfl_xor(p2, 2); p3 += __shfl_xor(p3, 2);

            float w0 = __expf(p0 + d0), w1 = __expf(p1 + d1);
            float w2 = __expf(p2 + d2), w3 = __expf(p3 + d3);
            vacc(u0, w0, sden, a0, a1, a2, a3);
            vacc(u1, w1, sden, a0, a1, a2, a3);
            vacc(u2, w2, sden, a0, a1, a2, a3);
            vacc(u3, w3, sden, a0, a1, a2, a3);
        }
        if (i + 2 < end) {                  // 2-deep cleanup
            int s0 = ssrc[i], s1 = ssrc[i + 2];
            uint4 u0 = *(const uint4*)(qv + (size_t)s0 * 256 + l * 8);
            uint4 u1 = *(const uint4*)(qv + (size_t)s1 * 256 + l * 8);
            float d0 = bf2f(dp16[(size_t)i * 8 + h]);
            float d1 = bf2f(dp16[(size_t)(i + 2) * 8 + h]);
            float p0 = qdot(u0, kv), p1 = qdot(u1, kv);
            p0 += __shfl_xor(p0, 1); p1 += __shfl_xor(p1, 1);
            p0 += __shfl_xor(p0, 2); p1 += __shfl_xor(p1, 2);
            float w0 = __expf(p0 + d0), w1 = __expf(p1 + d1);
            vacc(u0, w0, sden, a0, a1, a2, a3);
            vacc(u1, w1, sden, a0, a1, a2, a3);
            i += 4;
        }
        if (i < end) {                      // 1-edge tail
            int s0 = ssrc[i];
            uint4 u0 = *(const uint4*)(qv + (size_t)s0 * 256 + l * 8);
            float d0 = bf2f(dp16[(size_t)i * 8 + h]);
            float p0 = qdot(u0, kv);
            p0 += __shfl_xor(p0, 1); p0 += __shfl_xor(p0, 2);
            float w0 = __expf(p0 + d0);
            vacc(u0, w0, sden, a0, a1, a2, a3);
        }

        sden += __shfl_xor(sden, 32);
        a0 += __shfl_xor(a0, 32);
        a1 += __shfl_xor(a1, 32);
        a2 += __shfl_xor(a2, 32);
        a3 += __shfl_xor(a3, 32);

        const float inv = (end > beg) ? 1.f / sden : 0.f;
        if (half == 0)
            *(float4*)&ag[wv * 16 + ni][4 * l] =
                make_float4(a0 * inv, a1 * inv, a2 * inv, a3 * inv);
    }
    __syncthreads();

    // ---- phase 2: out = nf + ag @ W_out^T + b_out (MFMA bf16x3) ----
    const int mrow = lane & 15;
    const int kg   = lane >> 4;
    const float* arow = &ag[wv * 16 + mrow][kg * 8];

    short8 ahi[4], alo[4];
    #pragma unroll
    for (int t = 0; t < 4; t++) {
        float4 x0 = *(const float4*)(arow + t * 32);
        float4 x1 = *(const float4*)(arow + t * 32 + 4);
        float xn[8] = {x0.x, x0.y, x0.z, x0.w, x1.x, x1.y, x1.z, x1.w};
        #pragma unroll
        for (int j = 0; j < 8; j++) {
            unsigned short hh = f2bf_rne(xn[j]);
            ahi[t][j] = (short)hh;
            alo[t][j] = (short)f2bf_rne(xn[j] - bf2f(hh));
        }
    }

    int boff[4];
    #pragma unroll
    for (int t = 0; t < 4; t++)
        boff[t] = (mrow * 256 + (kg + 4 * t) * 16) ^ ((mrow & 7) << 4);

    const int nbw = nbase + wv * 16;
    for (int nt = 0; nt < TO; ++nt) {
        const char* base = (const char*)wo_t + (size_t)nt * 8192;
        f32x4 acc0 = {0.f, 0.f, 0.f, 0.f};
        f32x4 acc1 = {0.f, 0.f, 0.f, 0.f};
        #pragma unroll
        for (int t = 0; t < 4; t++) {
            short8 bh = *(const short8*)(base + boff[t]);
            short8 bl = *(const short8*)(base + 4096 + boff[t]);
            acc0 = __builtin_amdgcn_mfma_f32_16x16x32_bf16(ahi[t], bh, acc0, 0, 0, 0);
            acc1 = __builtin_amdgcn_mfma_f32_16x16x32_bf16(alo[t], bh, acc1, 0, 0, 0);
            acc0 = __builtin_amdgcn_mfma_f32_16x16x32_bf16(ahi[t], bl, acc0, 0, 0, 0);
        }

        const int col = nt * 16 + mrow;
        float bias = bout[col];
        #pragma unroll
        for (int r = 0; r < 4; r++) {
            int node = nbw + kg * 4 + r;
            if (node < N_NODES)
                out[(size_t)node * D + col] =
                    nf[(size_t)node * D + col] + bias + acc0[r] + acc1[r];
        }
    }
}

// ---------------------------------------------------------------------------
// launch
// ---------------------------------------------------------------------------
extern "C" void kernel_launch(void* const* d_in, const int* in_sizes, int n_in,
                              void* d_out, int out_size, void* d_ws, size_t ws_size,
                              hipStream_t stream) {
    const float* nf    = (const float*)d_in[0];
    const float* dist  = (const float*)d_in[1];
    const float* path  = (const float*)d_in[2];
    const float* gamma = (const float*)d_in[3];
    const float* beta  = (const float*)d_in[4];
    const float* Wqkv  = (const float*)d_in[5];
    const float* bqkv  = (const float*)d_in[6];
    const float* Wout  = (const float*)d_in[7];
    const float* bout  = (const float*)d_in[8];
    const int*   src   = (const int*)d_in[9];
    const int*   dst   = (const int*)d_in[10];
    float* out = (float*)d_out;

    // workspace layout (16B-aligned chunks)
    unsigned short* qvb  = (unsigned short*)d_ws;            // N*256 bf16
    unsigned short* kb16 = qvb + (size_t)N_NODES * 256;      // N*128 bf16
    unsigned short* dps  = kb16 + (size_t)N_NODES * 128;     // E*8 bf16 (edge order)
    unsigned short* dp16 = dps + (size_t)N_EDGES * 8;        // E*8 bf16 (CSR order)
    int* ssrc      = (int*)(dp16 + (size_t)N_EDGES * 8);     // E
    int* rank      = ssrc + N_EDGES;                         // E
    int* cnt       = rank + N_EDGES;                         // N
    int* row_start = cnt + N_NODES;                          // N+1
    int* bsum      = row_start + N_NODES + 1;                // SCG, pad to 64
    uintptr_t p = (uintptr_t)(bsum + 64);
    p = (p + 15) & ~(uintptr_t)15;
    unsigned short* wq_t = (unsigned short*)p;               // 24 tiles * 8KB
    unsigned short* wo_t = wq_t + TQ * 4096;                 // 8 tiles * 8KB

    (void)in_sizes; (void)n_in; (void)out_size; (void)ws_size;

    hipLaunchKernelGGL(k_prep, dim3((N_NODES + 255) / 256), dim3(256), 0, stream,
                       Wqkv, Wout, wq_t, wo_t, cnt);

    hipLaunchKernelGGL(k_hist, dim3((N_EDGES / 4 + 255) / 256), dim3(256), 0, stream,
                       dst, dist, path, cnt, rank, dps);
    hipLaunchKernelGGL(k_scan1, dim3(SCG), dim3(SCB), 0, stream,
                       cnt, row_start, bsum);
    hipLaunchKernelGGL(k_scan2, dim3(SCG), dim3(SCB), 0, stream,
                       bsum, row_start);
    hipLaunchKernelGGL(k_fill, dim3((N_EDGES / 4 + 255) / 256), dim3(256), 0, stream,
                       src, dst, rank, row_start, dps, ssrc, dp16);

    hipLaunchKernelGGL(k_ln_qkv, dim3((N_NODES + 63) / 64), dim3(256), 0, stream,
                       nf, gamma, beta, wq_t, bqkv, qvb, kb16);

    hipLaunchKernelGGL(k_gather_out, dim3((N_NODES + 63) / 64), dim3(256), 0, stream,
                       qvb, kb16, dp16, row_start, ssrc, wo_t, bout, nf, out);
}

// Round 21
// 200.778 us; speedup vs baseline: 1.0039x; 1.0039x over previous
//
#include <hip/hip_runtime.h>
#include <math.h>

#define N_NODES 50000
#define N_EDGES 800000
#define D 128
#define NH 8
#define EPS 1e-5f
#define QSCALE 0.08838834764831845f  // 128^-0.5

#define TQ 24   // 16-col tiles in W_qkv (384 cols)
#define TO 8    // 16-col tiles in W_out (128 cols)

typedef __attribute__((ext_vector_type(8))) short short8;
typedef __attribute__((ext_vector_type(4))) float f32x4;

// bf16 round-to-nearest-even helpers (bit-pattern in ushort)
__device__ __forceinline__ unsigned short f2bf_rne(float f) {
    unsigned int u = __float_as_uint(f);
    u += 0x7fff + ((u >> 16) & 1);
    return (unsigned short)(u >> 16);
}
__device__ __forceinline__ float bf2f(unsigned short h) {
    return __uint_as_float(((unsigned int)h) << 16);
}
__device__ __forceinline__ float2 bfpair(unsigned int u) {
    return make_float2(__uint_as_float(u << 16),
                       __uint_as_float(u & 0xffff0000u));
}

// async global->LDS, 16B per lane.
__device__ __forceinline__ void gload_lds16(const void* g, void* l) {
    __builtin_amdgcn_global_load_lds(
        (const __attribute__((address_space(1))) unsigned int*)g,
        (__attribute__((address_space(3))) unsigned int*)l, 16, 0, 0);
}

// gather helpers: q-dot and weighted-v accumulate from one packed uint4
__device__ __forceinline__ float qdot(uint4 u, float4 kv) {
    float2 q0 = bfpair(u.x), q1 = bfpair(u.z);
    return q0.x * kv.x + q0.y * kv.y + q1.x * kv.z + q1.y * kv.w;
}
__device__ __forceinline__ void vacc(uint4 u, float w, float& sden,
                                     float& a0, float& a1, float& a2, float& a3) {
    float2 v0 = bfpair(u.y), v1 = bfpair(u.w);
    sden += w;
    a0 += w * v0.x; a1 += w * v0.y; a2 += w * v1.x; a3 += w * v1.y;
}

// ---------------------------------------------------------------------------
// K_prep (+zero fused): split W into bf16 hi/lo, tiled + pre-swizzled; also
// zeroes the histogram buffer.
// ---------------------------------------------------------------------------
__global__ void k_prep(const float* __restrict__ Wqkv, const float* __restrict__ Wout,
                       unsigned short* __restrict__ wq_t, unsigned short* __restrict__ wo_t,
                       int* __restrict__ cnt) {
    const int i = blockIdx.x * blockDim.x + threadIdx.x;
    if (i < N_NODES) cnt[i] = 0;
    if (i < TQ * 256) {
        const int nt = i >> 8, r = (i >> 4) & 15, c8 = i & 15;
        const float* s = Wqkv + (size_t)(nt * 16 + r) * D + c8 * 8;
        short8 h8, l8;
        #pragma unroll
        for (int j = 0; j < 8; j++) {
            float w = s[j];
            unsigned short h = f2bf_rne(w);
            h8[j] = (short)h;
            l8[j] = (short)f2bf_rne(w - bf2f(h));
        }
        const int off = (r * 256 + c8 * 16) ^ ((r & 7) << 4);
        char* base = (char*)wq_t + (size_t)nt * 8192;
        *(short8*)(base + off)        = h8;
        *(short8*)(base + 4096 + off) = l8;
    }
    if (i < TO * 256) {
        const int nt = i >> 8, r = (i >> 4) & 15, c8 = i & 15;
        const float* s = Wout + (size_t)(nt * 16 + r) * D + c8 * 8;
        short8 h8, l8;
        #pragma unroll
        for (int j = 0; j < 8; j++) {
            float w = s[j];
            unsigned short h = f2bf_rne(w);
            h8[j] = (short)h;
            l8[j] = (short)f2bf_rne(w - bf2f(h));
        }
        const int off = (r * 256 + c8 * 16) ^ ((r & 7) << 4);
        char* base = (char*)wo_t + (size_t)nt * 8192;
        *(short8*)(base + off)        = h8;
        *(short8*)(base + 4096 + off) = l8;
    }
}

// ---------------------------------------------------------------------------
// K_hist: histogram + per-edge rank + dist+path summed to bf16 dpsum
// (edge order, coalesced; hides under atomic-return latency).
// ---------------------------------------------------------------------------
__global__ void k_hist(const int* __restrict__ dst,
                       const float* __restrict__ dist, const float* __restrict__ path,
                       int* __restrict__ cnt, int* __restrict__ rank,
                       unsigned short* __restrict__ dps) {
    const int e0 = (blockIdx.x * blockDim.x + threadIdx.x) * 4;
    if (e0 >= N_EDGES) return;                  // N_EDGES % 4 == 0
    const int4 d4 = *(const int4*)(dst + e0);
    int r0 = atomicAdd(&cnt[d4.x], 1);
    int r1 = atomicAdd(&cnt[d4.y], 1);
    int r2 = atomicAdd(&cnt[d4.z], 1);
    int r3 = atomicAdd(&cnt[d4.w], 1);
    #pragma unroll
    for (int j = 0; j < 4; j++) {
        const int e = e0 + j;
        float4 da = *(const float4*)(dist + (size_t)e * 8);
        float4 db = *(const float4*)(dist + (size_t)e * 8 + 4);
        float4 pa = *(const float4*)(path + (size_t)e * 8);
        float4 pb = *(const float4*)(path + (size_t)e * 8 + 4);
        short8 w;
        w[0] = (short)f2bf_rne(da.x + pa.x);
        w[1] = (short)f2bf_rne(da.y + pa.y);
        w[2] = (short)f2bf_rne(da.z + pa.z);
        w[3] = (short)f2bf_rne(da.w + pa.w);
        w[4] = (short)f2bf_rne(db.x + pb.x);
        w[5] = (short)f2bf_rne(db.y + pb.y);
        w[6] = (short)f2bf_rne(db.z + pb.z);
        w[7] = (short)f2bf_rne(db.w + pb.w);
        *(short8*)(dps + (size_t)e * 8) = w;
    }
    *(int4*)(rank + e0) = make_int4(r0, r1, r2, r3);
}

// ---------------------------------------------------------------------------
// CSR scan (hierarchical, 2 kernels)
// ---------------------------------------------------------------------------
#define SCB 1024
#define SCG ((N_NODES + SCB - 1) / SCB)

__global__ void k_scan1(const int* __restrict__ cnt, int* __restrict__ row_start,
                        int* __restrict__ bsum) {
    __shared__ int wsum[16];
    const int tid = threadIdx.x, lane = tid & 63, wid = tid >> 6;
    const int gid = blockIdx.x * SCB + tid;
    const int v = (gid < N_NODES) ? cnt[gid] : 0;

    int x = v;
    #pragma unroll
    for (int off = 1; off < 64; off <<= 1) {
        int t = __shfl_up(x, off);
        if (lane >= off) x += t;
    }
    if (lane == 63) wsum[wid] = x;
    __syncthreads();
    if (wid == 0) {
        int w = (lane < 16) ? wsum[lane] : 0;
        #pragma unroll
        for (int off = 1; off < 16; off <<= 1) {
            int t = __shfl_up(w, off);
            if (lane >= off) w += t;
        }
        if (lane < 16) wsum[lane] = w;
    }
    __syncthreads();
    const int base = (wid > 0) ? wsum[wid - 1] : 0;
    const int incl = base + x;
    if (gid < N_NODES) row_start[gid] = incl - v;
    if (tid == SCB - 1) bsum[blockIdx.x] = incl;
}

__global__ void k_scan2(const int* __restrict__ bsum, int* __restrict__ row_start) {
    __shared__ int boff_s;
    const int tid = threadIdx.x;
    if (tid < 64) {
        int v = (tid < blockIdx.x) ? bsum[tid] : 0;
        #pragma unroll
        for (int off = 1; off < 64; off <<= 1) v += __shfl_xor(v, off);
        if (tid == 0) boff_s = v;
    }
    __syncthreads();
    const int gid = blockIdx.x * SCB + tid;
    if (gid < N_NODES) row_start[gid] += boff_s;
    if (gid == 0) row_start[N_NODES] = N_EDGES;
}

// ---------------------------------------------------------------------------
// K_fill: no atomics, no float math — pos = row_start[dst] + rank;
// copy ssrc (4B) + dpsum short8 (16B) to CSR position. 4 edges/thread.
// ---------------------------------------------------------------------------
__global__ void k_fill(const int* __restrict__ src, const int* __restrict__ dst,
                       const int* __restrict__ rank, const int* __restrict__ row_start,
                       const unsigned short* __restrict__ dps,
                       int* __restrict__ ssrc, unsigned short* __restrict__ dp16) {
    const int e0 = (blockIdx.x * blockDim.x + threadIdx.x) * 4;
    if (e0 >= N_EDGES) return;                  // N_EDGES % 4 == 0
    const int4 s4 = *(const int4*)(src + e0);
    const int4 d4 = *(const int4*)(dst + e0);
    const int4 r4 = *(const int4*)(rank + e0);
    int p0 = row_start[d4.x] + r4.x;
    int p1 = row_start[d4.y] + r4.y;
    int p2 = row_start[d4.z] + r4.z;
    int p3 = row_start[d4.w] + r4.w;
    short8 w0 = *(const short8*)(dps + (size_t)e0 * 8);
    short8 w1 = *(const short8*)(dps + (size_t)(e0 + 1) * 8);
    short8 w2 = *(const short8*)(dps + (size_t)(e0 + 2) * 8);
    short8 w3 = *(const short8*)(dps + (size_t)(e0 + 3) * 8);

    ssrc[p0] = s4.x;  *(short8*)(dp16 + (size_t)p0 * 8) = w0;
    ssrc[p1] = s4.y;  *(short8*)(dp16 + (size_t)p1 * 8) = w1;
    ssrc[p2] = s4.z;  *(short8*)(dp16 + (size_t)p2 * 8) = w2;
    ssrc[p3] = s4.w;  *(short8*)(dp16 + (size_t)p3 * 8) = w3;
}

// ---------------------------------------------------------------------------
// K1: LayerNorm + QKV projection via MFMA bf16x3, LDS-staged W (unchanged).
// ---------------------------------------------------------------------------
__launch_bounds__(256)
__global__ void k_ln_qkv(const float* __restrict__ nf, const float* __restrict__ gamma,
                         const float* __restrict__ beta,
                         const unsigned short* __restrict__ wq_t,
                         const float* __restrict__ bqkv,
                         unsigned short* __restrict__ qv,
                         unsigned short* __restrict__ kb16) {
    __shared__ __align__(16) char lds[2][8192];
    const int lane  = threadIdx.x & 63;
    const int wv    = threadIdx.x >> 6;
    const int nbase = blockIdx.x * 64 + wv * 16;
    const int mrow  = lane & 15;
    const int kg    = lane >> 4;

    int gn = nbase + mrow;
    if (gn >= N_NODES) gn = N_NODES - 1;
    const float* xrow = nf + (size_t)gn * D + kg * 8;
    float4 xa[4], xb[4];
    #pragma unroll
    for (int t = 0; t < 4; t++) {
        xa[t] = *(const float4*)(xrow + t * 32);
        xb[t] = *(const float4*)(xrow + t * 32 + 4);
    }
    float s = 0.f, ss = 0.f;
    #pragma unroll
    for (int t = 0; t < 4; t++) {
        s  += xa[t].x + xa[t].y + xa[t].z + xa[t].w
            + xb[t].x + xb[t].y + xb[t].z + xb[t].w;
        ss += xa[t].x * xa[t].x + xa[t].y * xa[t].y + xa[t].z * xa[t].z + xa[t].w * xa[t].w
            + xb[t].x * xb[t].x + xb[t].y * xb[t].y + xb[t].z * xb[t].z + xb[t].w * xb[t].w;
    }
    s += __shfl_xor(s, 16); ss += __shfl_xor(ss, 16);
    s += __shfl_xor(s, 32); ss += __shfl_xor(ss, 32);
    float mu   = s * (1.f / 128.f);
    float var  = ss * (1.f / 128.f) - mu * mu;
    float rstd = rsqrtf(var + EPS);

    short8 ahi[4], alo[4];
    #pragma unroll
    for (int t = 0; t < 4; t++) {
        const float* gp = gamma + kg * 8 + t * 32;
        const float* bp = beta  + kg * 8 + t * 32;
        float4 g0 = *(const float4*)gp, g1 = *(const float4*)(gp + 4);
        float4 b0 = *(const float4*)bp, b1 = *(const float4*)(bp + 4);
        float xn[8];
        xn[0] = (xa[t].x - mu) * rstd * g0.x + b0.x;
        xn[1] = (xa[t].y - mu) * rstd * g0.y + b0.y;
        xn[2] = (xa[t].z - mu) * rstd * g0.z + b0.z;
        xn[3] = (xa[t].w - mu) * rstd * g0.w + b0.w;
        xn[4] = (xb[t].x - mu) * rstd * g1.x + b1.x;
        xn[5] = (xb[t].y - mu) * rstd * g1.y + b1.y;
        xn[6] = (xb[t].z - mu) * rstd * g1.z + b1.z;
        xn[7] = (xb[t].w - mu) * rstd * g1.w + b1.w;
        #pragma unroll
        for (int j = 0; j < 8; j++) {
            unsigned short h = f2bf_rne(xn[j]);
            ahi[t][j] = (short)h;
            alo[t][j] = (short)f2bf_rne(xn[j] - bf2f(h));
        }
    }

    int boff[4];
    #pragma unroll
    for (int t = 0; t < 4; t++)
        boff[t] = (mrow * 256 + (kg + 4 * t) * 16) ^ ((mrow & 7) << 4);

    {
        const char* g0 = (const char*)wq_t + (size_t)0 * 8192 + wv * 2048 + lane * 16;
        gload_lds16(g0,        lds[0] + wv * 2048);
        gload_lds16(g0 + 1024, lds[0] + wv * 2048 + 1024);
    }
    __syncthreads();

    int cur = 0;
    for (int nt = 0; nt < TQ; ++nt) {
        if (nt + 1 < TQ) {
            const char* g0 = (const char*)wq_t + (size_t)(nt + 1) * 8192 + wv * 2048 + lane * 16;
            gload_lds16(g0,        lds[cur ^ 1] + wv * 2048);
            gload_lds16(g0 + 1024, lds[cur ^ 1] + wv * 2048 + 1024);
        }

        f32x4 acc0 = {0.f, 0.f, 0.f, 0.f};
        f32x4 acc1 = {0.f, 0.f, 0.f, 0.f};
        #pragma unroll
        for (int t = 0; t < 4; t++) {
            short8 bh = *(const short8*)(lds[cur] + boff[t]);
            short8 bl = *(const short8*)(lds[cur] + 4096 + boff[t]);
            acc0 = __builtin_amdgcn_mfma_f32_16x16x32_bf16(ahi[t], bh, acc0, 0, 0, 0);
            acc1 = __builtin_amdgcn_mfma_f32_16x16x32_bf16(alo[t], bh, acc1, 0, 0, 0);
            acc0 = __builtin_amdgcn_mfma_f32_16x16x32_bf16(ahi[t], bl, acc0, 0, 0, 0);
        }

        const int col = nt * 16 + mrow;
        float bias = bqkv[col];
        if (nt < 8) {                 // q -> bf16 qv, pre-scaled, dword-packed
            #pragma unroll
            for (int r = 0; r < 4; r++) {
                int node = nbase + kg * 4 + r;
                unsigned int hq = f2bf_rne((acc0[r] + acc1[r] + bias) * QSCALE);
                unsigned int ph = __shfl_xor((int)hq, 1);
                if (!(mrow & 1) && node < N_NODES) {
                    unsigned int u2 = (hq & 0xffffu) | (ph << 16);
                    *(unsigned int*)(qv + (size_t)node * 256 + ((col >> 1) << 2)) = u2;
                }
            }
        } else if (nt < 16) {         // k -> bf16 kb16, dword-packed
            #pragma unroll
            for (int r = 0; r < 4; r++) {
                int node = nbase + kg * 4 + r;
                unsigned int hq = f2bf_rne(acc0[r] + acc1[r] + bias);
                unsigned int ph = __shfl_xor((int)hq, 1);
                if (!(mrow & 1) && node < N_NODES) {
                    unsigned int u2 = (hq & 0xffffu) | (ph << 16);
                    int ck = col - 128;
                    *(unsigned int*)(kb16 + (size_t)node * 128 + (ck & ~1)) = u2;
                }
            }
        } else {                      // v -> bf16 qv, dword-packed
            #pragma unroll
            for (int r = 0; r < 4; r++) {
                int node = nbase + kg * 4 + r;
                unsigned int hq = f2bf_rne(acc0[r] + acc1[r] + bias);
                unsigned int ph = __shfl_xor((int)hq, 1);
                if (!(mrow & 1) && node < N_NODES) {
                    unsigned int u2 = (hq & 0xffffu) | (ph << 16);
                    int cv = col - 256;
                    *(unsigned int*)(qv + (size_t)node * 256 + ((cv >> 1) << 2) + 2) = u2;
                }
            }
        }

        __syncthreads();
        cur ^= 1;
    }
}

// ---------------------------------------------------------------------------
// K_gather: 4-deep pipeline per half-wave; K bf16 (R18 structure, unchanged —
// occupancy is sacred here: no LDS, 67% occupancy, ~59.5µs).
// ---------------------------------------------------------------------------
__launch_bounds__(256, 4)
__global__ void k_gather(const unsigned short* __restrict__ qv,
                         const unsigned short* __restrict__ kb16,
                         const unsigned short* __restrict__ dp16,
                         const int* __restrict__ row_start,
                         const int* __restrict__ ssrc,
                         float* __restrict__ agg) {
    const int node = blockIdx.x * 4 + (threadIdx.x >> 6);
    if (node >= N_NODES) return;
    const int lane = threadIdx.x & 63;
    const int half = lane >> 5;            // 0/1: alternate edges
    const int l    = lane & 31;            // dims 4l..4l+3
    const int h    = l >> 2;               // head (4 lanes/head)
    const int beg = row_start[node], end = row_start[node + 1];

    uint2 ku = *(const uint2*)(kb16 + (size_t)node * 128 + 4 * l);
    float2 k0 = bfpair(ku.x), k1 = bfpair(ku.y);
    const float4 kv = make_float4(k0.x, k0.y, k1.x, k1.y);
    float sden = 0.f, a0 = 0.f, a1 = 0.f, a2 = 0.f, a3 = 0.f;

    int i = beg + half;
    // ---- 4-deep main loop: edges i, i+2, i+4, i+6 per half ----
    for (; i + 6 < end; i += 8) {
        int s0 = ssrc[i], s1 = ssrc[i + 2], s2 = ssrc[i + 4], s3 = ssrc[i + 6];
        uint4 u0 = *(const uint4*)(qv + (size_t)s0 * 256 + l * 8);
        uint4 u1 = *(const uint4*)(qv + (size_t)s1 * 256 + l * 8);
        uint4 u2 = *(const uint4*)(qv + (size_t)s2 * 256 + l * 8);
        uint4 u3 = *(const uint4*)(qv + (size_t)s3 * 256 + l * 8);
        float d0 = bf2f(dp16[(size_t)i * 8 + h]);
        float d1 = bf2f(dp16[(size_t)(i + 2) * 8 + h]);
        float d2 = bf2f(dp16[(size_t)(i + 4) * 8 + h]);
        float d3 = bf2f(dp16[(size_t)(i + 6) * 8 + h]);

        float p0 = qdot(u0, kv), p1 = qdot(u1, kv);
        float p2 = qdot(u2, kv), p3 = qdot(u3, kv);
        p0 += __shfl_xor(p0, 1); p1 += __shfl_xor(p1, 1);
        p2 += __shfl_xor(p2, 1); p3 += __shfl_xor(p3, 1);
        p0 += __shfl_xor(p0, 2); p1 += __shfl_xor(p1, 2);
        p2 += __shfl_xor(p2, 2); p3 += __shfl_xor(p3, 2);

        float w0 = __expf(p0 + d0), w1 = __expf(p1 + d1);
        float w2 = __expf(p2 + d2), w3 = __expf(p3 + d3);
        vacc(u0, w0, sden, a0, a1, a2, a3);
        vacc(u1, w1, sden, a0, a1, a2, a3);
        vacc(u2, w2, sden, a0, a1, a2, a3);
        vacc(u3, w3, sden, a0, a1, a2, a3);
    }
    // ---- 2-deep cleanup ----
    if (i + 2 < end) {
        int s0 = ssrc[i], s1 = ssrc[i + 2];
        uint4 u0 = *(const uint4*)(qv + (size_t)s0 * 256 + l * 8);
        uint4 u1 = *(const uint4*)(qv + (size_t)s1 * 256 + l * 8);
        float d0 = bf2f(dp16[(size_t)i * 8 + h]);
        float d1 = bf2f(dp16[(size_t)(i + 2) * 8 + h]);
        float p0 = qdot(u0, kv), p1 = qdot(u1, kv);
        p0 += __shfl_xor(p0, 1); p1 += __shfl_xor(p1, 1);
        p0 += __shfl_xor(p0, 2); p1 += __shfl_xor(p1, 2);
        float w0 = __expf(p0 + d0), w1 = __expf(p1 + d1);
        vacc(u0, w0, sden, a0, a1, a2, a3);
        vacc(u1, w1, sden, a0, a1, a2, a3);
        i += 4;
    }
    // ---- 1-edge tail ----
    if (i < end) {
        int s0 = ssrc[i];
        uint4 u0 = *(const uint4*)(qv + (size_t)s0 * 256 + l * 8);
        float d0 = bf2f(dp16[(size_t)i * 8 + h]);
        float p0 = qdot(u0, kv);
        p0 += __shfl_xor(p0, 1); p0 += __shfl_xor(p0, 2);
        float w0 = __expf(p0 + d0);
        vacc(u0, w0, sden, a0, a1, a2, a3);
    }

    // combine the two halves (same node)
    sden += __shfl_xor(sden, 32);
    a0 += __shfl_xor(a0, 32);
    a1 += __shfl_xor(a1, 32);
    a2 += __shfl_xor(a2, 32);
    a3 += __shfl_xor(a3, 32);

    const float inv = (end > beg) ? 1.f / sden : 0.f;
    if (half == 0) {
        float4 r = make_float4(a0 * inv, a1 * inv, a2 * inv, a3 * inv);
        *(float4*)(agg + (size_t)node * D + 4 * l) = r;
    }
}

// ---------------------------------------------------------------------------
// K5 (R21): out = nf + agg @ W_out.T + b_out, MFMA bf16x3, B-fragments read
// DIRECTLY from L2-hot pre-swizzled wo_t (64KB shared by all blocks) — no
// LDS, no barriers (addressing verified correct by R20's fused phase 2).
// ---------------------------------------------------------------------------
__launch_bounds__(256)
__global__ void k_out(const float* __restrict__ agg,
                      const unsigned short* __restrict__ wo_t,
                      const float* __restrict__ bout, const float* __restrict__ nf,
                      float* __restrict__ out) {
    const int lane  = threadIdx.x & 63;
    const int wv    = threadIdx.x >> 6;
    const int nbase = blockIdx.x * 64 + wv * 16;
    const int mrow  = lane & 15;
    const int kg    = lane >> 4;

    int gn = nbase + mrow;
    if (gn >= N_NODES) gn = N_NODES - 1;
    const float* arow = agg + (size_t)gn * D + kg * 8;

    short8 ahi[4], alo[4];
    #pragma unroll
    for (int t = 0; t < 4; t++) {
        float4 x0 = *(const float4*)(arow + t * 32);
        float4 x1 = *(const float4*)(arow + t * 32 + 4);
        float xn[8] = {x0.x, x0.y, x0.z, x0.w, x1.x, x1.y, x1.z, x1.w};
        #pragma unroll
        for (int j = 0; j < 8; j++) {
            unsigned short h = f2bf_rne(xn[j]);
            ahi[t][j] = (short)h;
            alo[t][j] = (short)f2bf_rne(xn[j] - bf2f(h));
        }
    }

    int boff[4];
    #pragma unroll
    for (int t = 0; t < 4; t++)
        boff[t] = (mrow * 256 + (kg + 4 * t) * 16) ^ ((mrow & 7) << 4);

    for (int nt = 0; nt < TO; ++nt) {
        const char* base = (const char*)wo_t + (size_t)nt * 8192;
        f32x4 acc0 = {0.f, 0.f, 0.f, 0.f};
        f32x4 acc1 = {0.f, 0.f, 0.f, 0.f};
        #pragma unroll
        for (int t = 0; t < 4; t++) {
            short8 bh = *(const short8*)(base + boff[t]);
            short8 bl = *(const short8*)(base + 4096 + boff[t]);
            acc0 = __builtin_amdgcn_mfma_f32_16x16x32_bf16(ahi[t], bh, acc0, 0, 0, 0);
            acc1 = __builtin_amdgcn_mfma_f32_16x16x32_bf16(alo[t], bh, acc1, 0, 0, 0);
            acc0 = __builtin_amdgcn_mfma_f32_16x16x32_bf16(ahi[t], bl, acc0, 0, 0, 0);
        }

        const int col = nt * 16 + mrow;
        float bias = bout[col];
        #pragma unroll
        for (int r = 0; r < 4; r++) {
            int node = nbase + kg * 4 + r;
            if (node < N_NODES)
                out[(size_t)node * D + col] =
                    nf[(size_t)node * D + col] + bias + acc0[r] + acc1[r];
        }
    }
}

// ---------------------------------------------------------------------------
// launch
// ---------------------------------------------------------------------------
extern "C" void kernel_launch(void* const* d_in, const int* in_sizes, int n_in,
                              void* d_out, int out_size, void* d_ws, size_t ws_size,
                              hipStream_t stream) {
    const float* nf    = (const float*)d_in[0];
    const float* dist  = (const float*)d_in[1];
    const float* path  = (const float*)d_in[2];
    const float* gamma = (const float*)d_in[3];
    const float* beta  = (const float*)d_in[4];
    const float* Wqkv  = (const float*)d_in[5];
    const float* bqkv  = (const float*)d_in[6];
    const float* Wout  = (const float*)d_in[7];
    const float* bout  = (const float*)d_in[8];
    const int*   src   = (const int*)d_in[9];
    const int*   dst   = (const int*)d_in[10];
    float* out = (float*)d_out;

    // workspace layout (16B-aligned chunks)
    float* agg = (float*)d_ws;                               // N*128 f32
    unsigned short* qvb  = (unsigned short*)(agg + (size_t)N_NODES * D);  // N*256
    unsigned short* kb16 = qvb + (size_t)N_NODES * 256;      // N*128 bf16
    unsigned short* dps  = kb16 + (size_t)N_NODES * 128;     // E*8 bf16 (edge order)
    unsigned short* dp16 = dps + (size_t)N_EDGES * 8;        // E*8 bf16 (CSR order)
    int* ssrc      = (int*)(dp16 + (size_t)N_EDGES * 8);     // E
    int* rank      = ssrc + N_EDGES;                         // E
    int* cnt       = rank + N_EDGES;                         // N
    int* row_start = cnt + N_NODES;                          // N+1
    int* bsum      = row_start + N_NODES + 1;                // SCG, pad to 64
    uintptr_t p = (uintptr_t)(bsum + 64);
    p = (p + 15) & ~(uintptr_t)15;
    unsigned short* wq_t = (unsigned short*)p;               // 24 tiles * 8KB
    unsigned short* wo_t = wq_t + TQ * 4096;                 // 8 tiles * 8KB

    (void)in_sizes; (void)n_in; (void)out_size; (void)ws_size;

    hipLaunchKernelGGL(k_prep, dim3((N_NODES + 255) / 256), dim3(256), 0, stream,
                       Wqkv, Wout, wq_t, wo_t, cnt);

    hipLaunchKernelGGL(k_hist, dim3((N_EDGES / 4 + 255) / 256), dim3(256), 0, stream,
                       dst, dist, path, cnt, rank, dps);
    hipLaunchKernelGGL(k_scan1, dim3(SCG), dim3(SCB), 0, stream,
                       cnt, row_start, bsum);
    hipLaunchKernelGGL(k_scan2, dim3(SCG), dim3(SCB), 0, stream,
                       bsum, row_start);
    hipLaunchKernelGGL(k_fill, dim3((N_EDGES / 4 + 255) / 256), dim3(256), 0, stream,
                       src, dst, rank, row_start, dps, ssrc, dp16);

    hipLaunchKernelGGL(k_ln_qkv, dim3((N_NODES + 63) / 64), dim3(256), 0, stream,
                       nf, gamma, beta, wq_t, bqkv, qvb, kb16);

    hipLaunchKernelGGL(k_gather, dim3((N_NODES + 3) / 4), dim3(256), 0, stream,
                       qvb, kb16, dp16, row_start, ssrc, agg);

    hipLaunchKernelGGL(k_out, dim3((N_NODES + 63) / 64), dim3(256), 0, stream,
                       agg, wo_t, bout, nf, out);
}

// Round 22
// 187.056 us; speedup vs baseline: 1.0776x; 1.0734x over previous
//
#include <hip/hip_runtime.h>
#include <math.h>

#define N_NODES 50000
#define N_EDGES 800000
#define D 128
#define NH 8
#define EPS 1e-5f
#define QSCALE 0.08838834764831845f  // 128^-0.5

#define TQ 24   // 16-col tiles in W_qkv (384 cols)
#define TO 8    // 16-col tiles in W_out (128 cols)

#define HIST_BLOCKS ((N_EDGES / 4 + 255) / 256)   // 782
#define LN_BLOCKS   ((N_NODES + 63) / 64)         // 782

typedef __attribute__((ext_vector_type(8))) short short8;
typedef __attribute__((ext_vector_type(4))) float f32x4;

// bf16 round-to-nearest-even helpers (bit-pattern in ushort)
__device__ __forceinline__ unsigned short f2bf_rne(float f) {
    unsigned int u = __float_as_uint(f);
    u += 0x7fff + ((u >> 16) & 1);
    return (unsigned short)(u >> 16);
}
__device__ __forceinline__ float bf2f(unsigned short h) {
    return __uint_as_float(((unsigned int)h) << 16);
}
__device__ __forceinline__ float2 bfpair(unsigned int u) {
    return make_float2(__uint_as_float(u << 16),
                       __uint_as_float(u & 0xffff0000u));
}

// async global->LDS, 16B per lane.
__device__ __forceinline__ void gload_lds16(const void* g, void* l) {
    __builtin_amdgcn_global_load_lds(
        (const __attribute__((address_space(1))) unsigned int*)g,
        (__attribute__((address_space(3))) unsigned int*)l, 16, 0, 0);
}

// gather helpers: q-dot and weighted-v accumulate from one packed uint4
__device__ __forceinline__ float qdot(uint4 u, float4 kv) {
    float2 q0 = bfpair(u.x), q1 = bfpair(u.z);
    return q0.x * kv.x + q0.y * kv.y + q1.x * kv.z + q1.y * kv.w;
}
__device__ __forceinline__ void vacc(uint4 u, float w, float& sden,
                                     float& a0, float& a1, float& a2, float& a3) {
    float2 v0 = bfpair(u.y), v1 = bfpair(u.w);
    sden += w;
    a0 += w * v0.x; a1 += w * v0.y; a2 += w * v1.x; a3 += w * v1.y;
}

// ---------------------------------------------------------------------------
// K_prep (+zero fused): split W into bf16 hi/lo, tiled + pre-swizzled; also
// zeroes the histogram buffer.
// ---------------------------------------------------------------------------
__global__ void k_prep(const float* __restrict__ Wqkv, const float* __restrict__ Wout,
                       unsigned short* __restrict__ wq_t, unsigned short* __restrict__ wo_t,
                       int* __restrict__ cnt) {
    const int i = blockIdx.x * blockDim.x + threadIdx.x;
    if (i < N_NODES) cnt[i] = 0;
    if (i < TQ * 256) {
        const int nt = i >> 8, r = (i >> 4) & 15, c8 = i & 15;
        const float* s = Wqkv + (size_t)(nt * 16 + r) * D + c8 * 8;
        short8 h8, l8;
        #pragma unroll
        for (int j = 0; j < 8; j++) {
            float w = s[j];
            unsigned short h = f2bf_rne(w);
            h8[j] = (short)h;
            l8[j] = (short)f2bf_rne(w - bf2f(h));
        }
        const int off = (r * 256 + c8 * 16) ^ ((r & 7) << 4);
        char* base = (char*)wq_t + (size_t)nt * 8192;
        *(short8*)(base + off)        = h8;
        *(short8*)(base + 4096 + off) = l8;
    }
    if (i < TO * 256) {
        const int nt = i >> 8, r = (i >> 4) & 15, c8 = i & 15;
        const float* s = Wout + (size_t)(nt * 16 + r) * D + c8 * 8;
        short8 h8, l8;
        #pragma unroll
        for (int j = 0; j < 8; j++) {
            float w = s[j];
            unsigned short h = f2bf_rne(w);
            h8[j] = (short)h;
            l8[j] = (short)f2bf_rne(w - bf2f(h));
        }
        const int off = (r * 256 + c8 * 16) ^ ((r & 7) << 4);
        char* base = (char*)wo_t + (size_t)nt * 8192;
        *(short8*)(base + off)        = h8;
        *(short8*)(base + 4096 + off) = l8;
    }
}

// ---------------------------------------------------------------------------
// K_histln (R22): hist and ln_qkv are data-independent — run them in ONE
// launch via block-range specialization so the atomic-LATENCY-bound hist
// overlaps the compute-bound ln_qkv on the same CUs (separate pipes, m114:
// time ~ max not sum). No inter-block communication -> no coherence hazard.
// ---------------------------------------------------------------------------
__launch_bounds__(256)
__global__ void k_histln(const int* __restrict__ dst,
                         const float* __restrict__ dist, const float* __restrict__ path,
                         int* __restrict__ cnt, int* __restrict__ rank,
                         unsigned short* __restrict__ dps,
                         const float* __restrict__ nf, const float* __restrict__ gamma,
                         const float* __restrict__ beta,
                         const unsigned short* __restrict__ wq_t,
                         const float* __restrict__ bqkv,
                         unsigned short* __restrict__ qv,
                         unsigned short* __restrict__ kb16) {
    __shared__ __align__(16) char lds[2][8192];

    if (blockIdx.x < HIST_BLOCKS) {
        // ================= hist path =================
        const int e0 = (blockIdx.x * 256 + threadIdx.x) * 4;
        if (e0 >= N_EDGES) return;              // N_EDGES % 4 == 0
        const int4 d4 = *(const int4*)(dst + e0);
        int r0 = atomicAdd(&cnt[d4.x], 1);
        int r1 = atomicAdd(&cnt[d4.y], 1);
        int r2 = atomicAdd(&cnt[d4.z], 1);
        int r3 = atomicAdd(&cnt[d4.w], 1);
        #pragma unroll
        for (int j = 0; j < 4; j++) {
            const int e = e0 + j;
            float4 da = *(const float4*)(dist + (size_t)e * 8);
            float4 db = *(const float4*)(dist + (size_t)e * 8 + 4);
            float4 pa = *(const float4*)(path + (size_t)e * 8);
            float4 pb = *(const float4*)(path + (size_t)e * 8 + 4);
            short8 w;
            w[0] = (short)f2bf_rne(da.x + pa.x);
            w[1] = (short)f2bf_rne(da.y + pa.y);
            w[2] = (short)f2bf_rne(da.z + pa.z);
            w[3] = (short)f2bf_rne(da.w + pa.w);
            w[4] = (short)f2bf_rne(db.x + pb.x);
            w[5] = (short)f2bf_rne(db.y + pb.y);
            w[6] = (short)f2bf_rne(db.z + pb.z);
            w[7] = (short)f2bf_rne(db.w + pb.w);
            *(short8*)(dps + (size_t)e * 8) = w;
        }
        *(int4*)(rank + e0) = make_int4(r0, r1, r2, r3);
        return;
    }

    // ================= ln_qkv path =================
    const int bid   = blockIdx.x - HIST_BLOCKS;
    const int lane  = threadIdx.x & 63;
    const int wv    = threadIdx.x >> 6;
    const int nbase = bid * 64 + wv * 16;
    const int mrow  = lane & 15;
    const int kg    = lane >> 4;

    int gn = nbase + mrow;
    if (gn >= N_NODES) gn = N_NODES - 1;
    const float* xrow = nf + (size_t)gn * D + kg * 8;
    float4 xa[4], xb[4];
    #pragma unroll
    for (int t = 0; t < 4; t++) {
        xa[t] = *(const float4*)(xrow + t * 32);
        xb[t] = *(const float4*)(xrow + t * 32 + 4);
    }
    float s = 0.f, ss = 0.f;
    #pragma unroll
    for (int t = 0; t < 4; t++) {
        s  += xa[t].x + xa[t].y + xa[t].z + xa[t].w
            + xb[t].x + xb[t].y + xb[t].z + xb[t].w;
        ss += xa[t].x * xa[t].x + xa[t].y * xa[t].y + xa[t].z * xa[t].z + xa[t].w * xa[t].w
            + xb[t].x * xb[t].x + xb[t].y * xb[t].y + xb[t].z * xb[t].z + xb[t].w * xb[t].w;
    }
    s += __shfl_xor(s, 16); ss += __shfl_xor(ss, 16);
    s += __shfl_xor(s, 32); ss += __shfl_xor(ss, 32);
    float mu   = s * (1.f / 128.f);
    float var  = ss * (1.f / 128.f) - mu * mu;
    float rstd = rsqrtf(var + EPS);

    short8 ahi[4], alo[4];
    #pragma unroll
    for (int t = 0; t < 4; t++) {
        const float* gp = gamma + kg * 8 + t * 32;
        const float* bp = beta  + kg * 8 + t * 32;
        float4 g0 = *(const float4*)gp, g1 = *(const float4*)(gp + 4);
        float4 b0 = *(const float4*)bp, b1 = *(const float4*)(bp + 4);
        float xn[8];
        xn[0] = (xa[t].x - mu) * rstd * g0.x + b0.x;
        xn[1] = (xa[t].y - mu) * rstd * g0.y + b0.y;
        xn[2] = (xa[t].z - mu) * rstd * g0.z + b0.z;
        xn[3] = (xa[t].w - mu) * rstd * g0.w + b0.w;
        xn[4] = (xb[t].x - mu) * rstd * g1.x + b1.x;
        xn[5] = (xb[t].y - mu) * rstd * g1.y + b1.y;
        xn[6] = (xb[t].z - mu) * rstd * g1.z + b1.z;
        xn[7] = (xb[t].w - mu) * rstd * g1.w + b1.w;
        #pragma unroll
        for (int j = 0; j < 8; j++) {
            unsigned short h = f2bf_rne(xn[j]);
            ahi[t][j] = (short)h;
            alo[t][j] = (short)f2bf_rne(xn[j] - bf2f(h));
        }
    }

    int boff[4];
    #pragma unroll
    for (int t = 0; t < 4; t++)
        boff[t] = (mrow * 256 + (kg + 4 * t) * 16) ^ ((mrow & 7) << 4);

    {
        const char* g0 = (const char*)wq_t + (size_t)0 * 8192 + wv * 2048 + lane * 16;
        gload_lds16(g0,        lds[0] + wv * 2048);
        gload_lds16(g0 + 1024, lds[0] + wv * 2048 + 1024);
    }
    __syncthreads();

    int cur = 0;
    for (int nt = 0; nt < TQ; ++nt) {
        if (nt + 1 < TQ) {
            const char* g0 = (const char*)wq_t + (size_t)(nt + 1) * 8192 + wv * 2048 + lane * 16;
            gload_lds16(g0,        lds[cur ^ 1] + wv * 2048);
            gload_lds16(g0 + 1024, lds[cur ^ 1] + wv * 2048 + 1024);
        }

        f32x4 acc0 = {0.f, 0.f, 0.f, 0.f};
        f32x4 acc1 = {0.f, 0.f, 0.f, 0.f};
        #pragma unroll
        for (int t = 0; t < 4; t++) {
            short8 bh = *(const short8*)(lds[cur] + boff[t]);
            short8 bl = *(const short8*)(lds[cur] + 4096 + boff[t]);
            acc0 = __builtin_amdgcn_mfma_f32_16x16x32_bf16(ahi[t], bh, acc0, 0, 0, 0);
            acc1 = __builtin_amdgcn_mfma_f32_16x16x32_bf16(alo[t], bh, acc1, 0, 0, 0);
            acc0 = __builtin_amdgcn_mfma_f32_16x16x32_bf16(ahi[t], bl, acc0, 0, 0, 0);
        }

        const int col = nt * 16 + mrow;
        float bias = bqkv[col];
        if (nt < 8) {                 // q -> bf16 qv, pre-scaled, dword-packed
            #pragma unroll
            for (int r = 0; r < 4; r++) {
                int node = nbase + kg * 4 + r;
                unsigned int hq = f2bf_rne((acc0[r] + acc1[r] + bias) * QSCALE);
                unsigned int ph = __shfl_xor((int)hq, 1);
                if (!(mrow & 1) && node < N_NODES) {
                    unsigned int u2 = (hq & 0xffffu) | (ph << 16);
                    *(unsigned int*)(qv + (size_t)node * 256 + ((col >> 1) << 2)) = u2;
                }
            }
        } else if (nt < 16) {         // k -> bf16 kb16, dword-packed
            #pragma unroll
            for (int r = 0; r < 4; r++) {
                int node = nbase + kg * 4 + r;
                unsigned int hq = f2bf_rne(acc0[r] + acc1[r] + bias);
                unsigned int ph = __shfl_xor((int)hq, 1);
                if (!(mrow & 1) && node < N_NODES) {
                    unsigned int u2 = (hq & 0xffffu) | (ph << 16);
                    int ck = col - 128;
                    *(unsigned int*)(kb16 + (size_t)node * 128 + (ck & ~1)) = u2;
                }
            }
        } else {                      // v -> bf16 qv, dword-packed
            #pragma unroll
            for (int r = 0; r < 4; r++) {
                int node = nbase + kg * 4 + r;
                unsigned int hq = f2bf_rne(acc0[r] + acc1[r] + bias);
                unsigned int ph = __shfl_xor((int)hq, 1);
                if (!(mrow & 1) && node < N_NODES) {
                    unsigned int u2 = (hq & 0xffffu) | (ph << 16);
                    int cv = col - 256;
                    *(unsigned int*)(qv + (size_t)node * 256 + ((cv >> 1) << 2) + 2) = u2;
                }
            }
        }

        __syncthreads();
        cur ^= 1;
    }
}

// ---------------------------------------------------------------------------
// CSR scan (hierarchical, 2 kernels)
// ---------------------------------------------------------------------------
#define SCB 1024
#define SCG ((N_NODES + SCB - 1) / SCB)

__global__ void k_scan1(const int* __restrict__ cnt, int* __restrict__ row_start,
                        int* __restrict__ bsum) {
    __shared__ int wsum[16];
    const int tid = threadIdx.x, lane = tid & 63, wid = tid >> 6;
    const int gid = blockIdx.x * SCB + tid;
    const int v = (gid < N_NODES) ? cnt[gid] : 0;

    int x = v;
    #pragma unroll
    for (int off = 1; off < 64; off <<= 1) {
        int t = __shfl_up(x, off);
        if (lane >= off) x += t;
    }
    if (lane == 63) wsum[wid] = x;
    __syncthreads();
    if (wid == 0) {
        int w = (lane < 16) ? wsum[lane] : 0;
        #pragma unroll
        for (int off = 1; off < 16; off <<= 1) {
            int t = __shfl_up(w, off);
            if (lane >= off) w += t;
        }
        if (lane < 16) wsum[lane] = w;
    }
    __syncthreads();
    const int base = (wid > 0) ? wsum[wid - 1] : 0;
    const int incl = base + x;
    if (gid < N_NODES) row_start[gid] = incl - v;
    if (tid == SCB - 1) bsum[blockIdx.x] = incl;
}

__global__ void k_scan2(const int* __restrict__ bsum, int* __restrict__ row_start) {
    __shared__ int boff_s;
    const int tid = threadIdx.x;
    if (tid < 64) {
        int v = (tid < blockIdx.x) ? bsum[tid] : 0;
        #pragma unroll
        for (int off = 1; off < 64; off <<= 1) v += __shfl_xor(v, off);
        if (tid == 0) boff_s = v;
    }
    __syncthreads();
    const int gid = blockIdx.x * SCB + tid;
    if (gid < N_NODES) row_start[gid] += boff_s;
    if (gid == 0) row_start[N_NODES] = N_EDGES;
}

// ---------------------------------------------------------------------------
// K_fill: no atomics, no float math — pos = row_start[dst] + rank;
// copy ssrc (4B) + dpsum short8 (16B) to CSR position. 4 edges/thread.
// ---------------------------------------------------------------------------
__global__ void k_fill(const int* __restrict__ src, const int* __restrict__ dst,
                       const int* __restrict__ rank, const int* __restrict__ row_start,
                       const unsigned short* __restrict__ dps,
                       int* __restrict__ ssrc, unsigned short* __restrict__ dp16) {
    const int e0 = (blockIdx.x * blockDim.x + threadIdx.x) * 4;
    if (e0 >= N_EDGES) return;                  // N_EDGES % 4 == 0
    const int4 s4 = *(const int4*)(src + e0);
    const int4 d4 = *(const int4*)(dst + e0);
    const int4 r4 = *(const int4*)(rank + e0);
    int p0 = row_start[d4.x] + r4.x;
    int p1 = row_start[d4.y] + r4.y;
    int p2 = row_start[d4.z] + r4.z;
    int p3 = row_start[d4.w] + r4.w;
    short8 w0 = *(const short8*)(dps + (size_t)e0 * 8);
    short8 w1 = *(const short8*)(dps + (size_t)(e0 + 1) * 8);
    short8 w2 = *(const short8*)(dps + (size_t)(e0 + 2) * 8);
    short8 w3 = *(const short8*)(dps + (size_t)(e0 + 3) * 8);

    ssrc[p0] = s4.x;  *(short8*)(dp16 + (size_t)p0 * 8) = w0;
    ssrc[p1] = s4.y;  *(short8*)(dp16 + (size_t)p1 * 8) = w1;
    ssrc[p2] = s4.z;  *(short8*)(dp16 + (size_t)p2 * 8) = w2;
    ssrc[p3] = s4.w;  *(short8*)(dp16 + (size_t)p3 * 8) = w3;
}

// ---------------------------------------------------------------------------
// K_gather: 4-deep pipeline per half-wave; K bf16 (unchanged — occupancy is
// sacred here: no LDS, 67% occupancy, ~59.5µs).
// ---------------------------------------------------------------------------
__launch_bounds__(256, 4)
__global__ void k_gather(const unsigned short* __restrict__ qv,
                         const unsigned short* __restrict__ kb16,
                         const unsigned short* __restrict__ dp16,
                         const int* __restrict__ row_start,
                         const int* __restrict__ ssrc,
                         float* __restrict__ agg) {
    const int node = blockIdx.x * 4 + (threadIdx.x >> 6);
    if (node >= N_NODES) return;
    const int lane = threadIdx.x & 63;
    const int half = lane >> 5;            // 0/1: alternate edges
    const int l    = lane & 31;            // dims 4l..4l+3
    const int h    = l >> 2;               // head (4 lanes/head)
    const int beg = row_start[node], end = row_start[node + 1];

    uint2 ku = *(const uint2*)(kb16 + (size_t)node * 128 + 4 * l);
    float2 k0 = bfpair(ku.x), k1 = bfpair(ku.y);
    const float4 kv = make_float4(k0.x, k0.y, k1.x, k1.y);
    float sden = 0.f, a0 = 0.f, a1 = 0.f, a2 = 0.f, a3 = 0.f;

    int i = beg + half;
    // ---- 4-deep main loop: edges i, i+2, i+4, i+6 per half ----
    for (; i + 6 < end; i += 8) {
        int s0 = ssrc[i], s1 = ssrc[i + 2], s2 = ssrc[i + 4], s3 = ssrc[i + 6];
        uint4 u0 = *(const uint4*)(qv + (size_t)s0 * 256 + l * 8);
        uint4 u1 = *(const uint4*)(qv + (size_t)s1 * 256 + l * 8);
        uint4 u2 = *(const uint4*)(qv + (size_t)s2 * 256 + l * 8);
        uint4 u3 = *(const uint4*)(qv + (size_t)s3 * 256 + l * 8);
        float d0 = bf2f(dp16[(size_t)i * 8 + h]);
        float d1 = bf2f(dp16[(size_t)(i + 2) * 8 + h]);
        float d2 = bf2f(dp16[(size_t)(i + 4) * 8 + h]);
        float d3 = bf2f(dp16[(size_t)(i + 6) * 8 + h]);

        float p0 = qdot(u0, kv), p1 = qdot(u1, kv);
        float p2 = qdot(u2, kv), p3 = qdot(u3, kv);
        p0 += __shfl_xor(p0, 1); p1 += __shfl_xor(p1, 1);
        p2 += __shfl_xor(p2, 1); p3 += __shfl_xor(p3, 1);
        p0 += __shfl_xor(p0, 2); p1 += __shfl_xor(p1, 2);
        p2 += __shfl_xor(p2, 2); p3 += __shfl_xor(p3, 2);

        float w0 = __expf(p0 + d0), w1 = __expf(p1 + d1);
        float w2 = __expf(p2 + d2), w3 = __expf(p3 + d3);
        vacc(u0, w0, sden, a0, a1, a2, a3);
        vacc(u1, w1, sden, a0, a1, a2, a3);
        vacc(u2, w2, sden, a0, a1, a2, a3);
        vacc(u3, w3, sden, a0, a1, a2, a3);
    }
    // ---- 2-deep cleanup ----
    if (i + 2 < end) {
        int s0 = ssrc[i], s1 = ssrc[i + 2];
        uint4 u0 = *(const uint4*)(qv + (size_t)s0 * 256 + l * 8);
        uint4 u1 = *(const uint4*)(qv + (size_t)s1 * 256 + l * 8);
        float d0 = bf2f(dp16[(size_t)i * 8 + h]);
        float d1 = bf2f(dp16[(size_t)(i + 2) * 8 + h]);
        float p0 = qdot(u0, kv), p1 = qdot(u1, kv);
        p0 += __shfl_xor(p0, 1); p1 += __shfl_xor(p1, 1);
        p0 += __shfl_xor(p0, 2); p1 += __shfl_xor(p1, 2);
        float w0 = __expf(p0 + d0), w1 = __expf(p1 + d1);
        vacc(u0, w0, sden, a0, a1, a2, a3);
        vacc(u1, w1, sden, a0, a1, a2, a3);
        i += 4;
    }
    // ---- 1-edge tail ----
    if (i < end) {
        int s0 = ssrc[i];
        uint4 u0 = *(const uint4*)(qv + (size_t)s0 * 256 + l * 8);
        float d0 = bf2f(dp16[(size_t)i * 8 + h]);
        float p0 = qdot(u0, kv);
        p0 += __shfl_xor(p0, 1); p0 += __shfl_xor(p0, 2);
        float w0 = __expf(p0 + d0);
        vacc(u0, w0, sden, a0, a1, a2, a3);
    }

    // combine the two halves (same node)
    sden += __shfl_xor(sden, 32);
    a0 += __shfl_xor(a0, 32);
    a1 += __shfl_xor(a1, 32);
    a2 += __shfl_xor(a2, 32);
    a3 += __shfl_xor(a3, 32);

    const float inv = (end > beg) ? 1.f / sden : 0.f;
    if (half == 0) {
        float4 r = make_float4(a0 * inv, a1 * inv, a2 * inv, a3 * inv);
        *(float4*)(agg + (size_t)node * D + 4 * l) = r;
    }
}

// ---------------------------------------------------------------------------
// K5: out = node_feature + agg @ W_out.T + b_out — LDS-staged (R18 version,
// known-good; the R21 L2-direct variant was not faster).
// ---------------------------------------------------------------------------
__launch_bounds__(256)
__global__ void k_out(const float* __restrict__ agg,
                      const unsigned short* __restrict__ wo_t,
                      const float* __restrict__ bout, const float* __restrict__ nf,
                      float* __restrict__ out) {
    __shared__ __align__(16) char lds[2][8192];
    const int lane  = threadIdx.x & 63;
    const int wv    = threadIdx.x >> 6;
    const int nbase = blockIdx.x * 64 + wv * 16;
    const int mrow  = lane & 15;
    const int kg    = lane >> 4;

    int gn = nbase + mrow;
    if (gn >= N_NODES) gn = N_NODES - 1;
    const float* arow = agg + (size_t)gn * D + kg * 8;

    short8 ahi[4], alo[4];
    #pragma unroll
    for (int t = 0; t < 4; t++) {
        float4 x0 = *(const float4*)(arow + t * 32);
        float4 x1 = *(const float4*)(arow + t * 32 + 4);
        float xn[8] = {x0.x, x0.y, x0.z, x0.w, x1.x, x1.y, x1.z, x1.w};
        #pragma unroll
        for (int j = 0; j < 8; j++) {
            unsigned short h = f2bf_rne(xn[j]);
            ahi[t][j] = (short)h;
            alo[t][j] = (short)f2bf_rne(xn[j] - bf2f(h));
        }
    }

    int boff[4];
    #pragma unroll
    for (int t = 0; t < 4; t++)
        boff[t] = (mrow * 256 + (kg + 4 * t) * 16) ^ ((mrow & 7) << 4);

    {
        const char* g0 = (const char*)wo_t + (size_t)0 * 8192 + wv * 2048 + lane * 16;
        gload_lds16(g0,        lds[0] + wv * 2048);
        gload_lds16(g0 + 1024, lds[0] + wv * 2048 + 1024);
    }
    __syncthreads();

    int cur = 0;
    for (int nt = 0; nt < TO; ++nt) {
        if (nt + 1 < TO) {
            const char* g0 = (const char*)wo_t + (size_t)(nt + 1) * 8192 + wv * 2048 + lane * 16;
            gload_lds16(g0,        lds[cur ^ 1] + wv * 2048);
            gload_lds16(g0 + 1024, lds[cur ^ 1] + wv * 2048 + 1024);
        }

        f32x4 acc0 = {0.f, 0.f, 0.f, 0.f};
        f32x4 acc1 = {0.f, 0.f, 0.f, 0.f};
        #pragma unroll
        for (int t = 0; t < 4; t++) {
            short8 bh = *(const short8*)(lds[cur] + boff[t]);
            short8 bl = *(const short8*)(lds[cur] + 4096 + boff[t]);
            acc0 = __builtin_amdgcn_mfma_f32_16x16x32_bf16(ahi[t], bh, acc0, 0, 0, 0);
            acc1 = __builtin_amdgcn_mfma_f32_16x16x32_bf16(alo[t], bh, acc1, 0, 0, 0);
            acc0 = __builtin_amdgcn_mfma_f32_16x16x32_bf16(ahi[t], bl, acc0, 0, 0, 0);
        }

        const int col = nt * 16 + mrow;
        float bias = bout[col];
        #pragma unroll
        for (int r = 0; r < 4; r++) {
            int node = nbase + kg * 4 + r;
            if (node < N_NODES)
                out[(size_t)node * D + col] =
                    nf[(size_t)node * D + col] + bias + acc0[r] + acc1[r];
        }

        __syncthreads();
        cur ^= 1;
    }
}

// ---------------------------------------------------------------------------
// launch
// ---------------------------------------------------------------------------
extern "C" void kernel_launch(void* const* d_in, const int* in_sizes, int n_in,
                              void* d_out, int out_size, void* d_ws, size_t ws_size,
                              hipStream_t stream) {
    const float* nf    = (const float*)d_in[0];
    const float* dist  = (const float*)d_in[1];
    const float* path  = (const float*)d_in[2];
    const float* gamma = (const float*)d_in[3];
    const float* beta  = (const float*)d_in[4];
    const float* Wqkv  = (const float*)d_in[5];
    const float* bqkv  = (const float*)d_in[6];
    const float* Wout  = (const float*)d_in[7];
    const float* bout  = (const float*)d_in[8];
    const int*   src   = (const int*)d_in[9];
    const int*   dst   = (const int*)d_in[10];
    float* out = (float*)d_out;

    // workspace layout (16B-aligned chunks)
    float* agg = (float*)d_ws;                               // N*128 f32
    unsigned short* qvb  = (unsigned short*)(agg + (size_t)N_NODES * D);  // N*256
    unsigned short* kb16 = qvb + (size_t)N_NODES * 256;      // N*128 bf16
    unsigned short* dps  = kb16 + (size_t)N_NODES * 128;     // E*8 bf16 (edge order)
    unsigned short* dp16 = dps + (size_t)N_EDGES * 8;        // E*8 bf16 (CSR order)
    int* ssrc      = (int*)(dp16 + (size_t)N_EDGES * 8);     // E
    int* rank      = ssrc + N_EDGES;                         // E
    int* cnt       = rank + N_EDGES;                         // N
    int* row_start = cnt + N_NODES;                          // N+1
    int* bsum      = row_start + N_NODES + 1;                // SCG, pad to 64
    uintptr_t p = (uintptr_t)(bsum + 64);
    p = (p + 15) & ~(uintptr_t)15;
    unsigned short* wq_t = (unsigned short*)p;               // 24 tiles * 8KB
    unsigned short* wo_t = wq_t + TQ * 4096;                 // 8 tiles * 8KB

    (void)in_sizes; (void)n_in; (void)out_size; (void)ws_size;

    hipLaunchKernelGGL(k_prep, dim3((N_NODES + 255) / 256), dim3(256), 0, stream,
                       Wqkv, Wout, wq_t, wo_t, cnt);

    hipLaunchKernelGGL(k_histln, dim3(HIST_BLOCKS + LN_BLOCKS), dim3(256), 0, stream,
                       dst, dist, path, cnt, rank, dps,
                       nf, gamma, beta, wq_t, bqkv, qvb, kb16);

    hipLaunchKernelGGL(k_scan1, dim3(SCG), dim3(SCB), 0, stream,
                       cnt, row_start, bsum);
    hipLaunchKernelGGL(k_scan2, dim3(SCG), dim3(SCB), 0, stream,
                       bsum, row_start);
    hipLaunchKernelGGL(k_fill, dim3((N_EDGES / 4 + 255) / 256), dim3(256), 0, stream,
                       src, dst, rank, row_start, dps, ssrc, dp16);

    hipLaunchKernelGGL(k_gather, dim3((N_NODES + 3) / 4), dim3(256), 0, stream,
                       qvb, kb16, dp16, row_start, ssrc, agg);

    hipLaunchKernelGGL(k_out, dim3((N_NODES + 63) / 64), dim3(256), 0, stream,
                       agg, wo_t, bout, nf, out);
}